// Round 5
// baseline (69.241 us; speedup 1.0000x reference)
//
#include <hip/hip_runtime.h>
#include <stdint.h>

typedef __attribute__((ext_vector_type(8))) short bfrag_t;   // 8 bf16
typedef __attribute__((ext_vector_type(4))) float floatx4;   // MFMA acc

// ---------------- ws layout (bytes) ----------------
#define WFRAG_OFF   0            // bf16 [16kt][18nt][64lane][8j]   = 294912
#define GB_OFF      294912       // f32 [32][128]                   = 16384
#define BU_OFF      311296       // f32 [128]
#define BS_OFF      311808       // f32 [32]
#define MEMFRAG_OFF 311936       // bf16 frag [8nt][64lane][8j]     = 8192
#define ACC_OFF     327680       // ncopy x (accw[4096] | accg[4096]) f32
#define XP_G_OFF    2424832      // bf16 [16384][128] = 4 MiB
#define U_G_OFF     6619136      // bf16 [16384][128] = 4 MiB
#define PR_G_OFF    10813440     // bf16 [16384][32]  = 1 MiB
#define WS_NEED     11862016

// ---------------- kernel A LDS layout ----------------
// A-tile [32r][1024B] = 32768 at 0 during GEMM; overlaid after:
#define A_RC   0                 // f32 [32][128] = 16384
#define A_XP   16384             // bf16 [32][128] = 8192
#define A_U    24576             // bf16 [32][128] = 8192
#define A_SC   32768             // f32 [32][32] = 4096
#define A_PR   36864             // bf16 frag [2mt][64][8] = 2048
#define A_PRL  38912             // bf16 [32][32] linear = 2048
#define A_LDS  40960

// ---------------- legacy (fallback) LDS layout ----------------
#define L_U     0
#define L_RC    8192
#define L_XPF   16384
#define L_SC    24576
#define L_PR    26624
#define L_PRT   27648
#define L_LDS   29696

__device__ __forceinline__ unsigned short f2bf(float f) {
    unsigned u = __float_as_uint(f);
    u += 0x7fffu + ((u >> 16) & 1u);
    return (unsigned short)(u >> 16);
}
__device__ __forceinline__ float bf2f(unsigned short h) {
    return __uint_as_float(((unsigned)h) << 16);
}
__device__ __forceinline__ float sigm(float v) {
    return __builtin_amdgcn_rcpf(1.0f + __expf(-v));
}
__device__ __forceinline__ void writefrag(unsigned short* wf, int k, int n, float v) {
    int kt = k >> 5, kk = k & 31;
    int lane = (n & 15) | ((kk >> 3) << 4);
    wf[(((kt * 18) + (n >> 4)) * 64 + lane) * 8 + (kk & 7)] = f2bf(v);
}

// ---------------- prep: frag weights, gate base, biases, mem frags, zero ----------------
__global__ __launch_bounds__(256) void prep_kernel(
    const float* __restrict__ memv, const float* __restrict__ w_in,
    const float* __restrict__ b_in, const float* __restrict__ w_gate,
    const float* __restrict__ b_gate, unsigned char* __restrict__ ws, int ncopy)
{
    int bid = blockIdx.x, t = threadIdx.x;
    unsigned short* wfrag = (unsigned short*)(ws + WFRAG_OFF);
    const float* wg2 = w_gate + 128 * 128;

    if (bid < 256) {
        __shared__ float wrow[2][128];
        int k0 = bid * 2;
        wrow[t >> 7][t & 127] = w_in[(size_t)(k0 + (t >> 7)) * 128 + (t & 127)];
        __syncthreads();
        for (int kl = 0; kl < 2; ++kl) {
            int k = k0 + kl;
            float v;
            if (t < 128) {
                v = wrow[kl][t];
            } else {
                int d = t - 128;
                float acc = 0.f;
                #pragma unroll 16
                for (int j = 0; j < 128; ++j) acc += wrow[kl][j] * wg2[j * 128 + d];
                v = acc;
            }
            writefrag(wfrag, k, t, v);
            if (t < 32) {
                float acc = 0.f;
                #pragma unroll 16
                for (int d = 0; d < 128; ++d) acc += wrow[kl][d] * memv[t * 128 + d];
                writefrag(wfrag, k, 256 + t, acc);
            }
        }
    } else if (bid < 272) {
        int idx = (bid - 256) * 256 + t;
        int s = idx >> 7, d = idx & 127;
        float acc = b_gate[d];
        #pragma unroll 16
        for (int k = 0; k < 128; ++k) acc += memv[s * 128 + k] * w_gate[k * 128 + d];
        ((float*)(ws + GB_OFF))[idx] = acc;
    } else if (bid == 272) {
        if (t < 128) {
            float acc = 0.f;
            #pragma unroll 16
            for (int j = 0; j < 128; ++j) acc += b_in[j] * wg2[j * 128 + t];
            ((float*)(ws + BU_OFF))[t] = acc;
        }
        if (t < 32) {
            float acc = 0.f;
            #pragma unroll 16
            for (int d = 0; d < 128; ++d) acc += b_in[d] * memv[t * 128 + d];
            ((float*)(ws + BS_OFF))[t] = acc;
        }
        unsigned short* mfr = (unsigned short*)(ws + MEMFRAG_OFF);
        for (int idx = t; idx < 4096; idx += 256) {
            int s = idx >> 7, d = idx & 127;
            mfr[((d >> 4) * 64 + ((d & 15) | (((s >> 3) & 3) << 4))) * 8 + (s & 7)]
                = f2bf(memv[idx]);
        }
    } else {
        int zb = bid - 273;    // 16 blocks
        float4* dst = (float4*)(ws + ACC_OFF + (size_t)zb * ncopy * 2048);
        int n4 = ncopy * 128;
        for (int i = t; i < n4; i += 256) dst[i] = (float4){0.f, 0.f, 0.f, 0.f};
    }
}

// ================= kernel A: LN + GEMM + softmax + read-GEMM + materialize =================
__global__ __launch_bounds__(256, 4) void gemm_kernel(
    const float* __restrict__ x,
    const float* __restrict__ ln_g, const float* __restrict__ ln_b,
    const float* __restrict__ b_in, unsigned char* __restrict__ ws,
    float* __restrict__ out)
{
    __shared__ char smem[A_LDS] __attribute__((aligned(16)));

    int tid = threadIdx.x;
    int w = tid >> 6, l = tid & 63;
    int lane_lo = l & 15, lane_hi = l >> 4;
    int row_base = blockIdx.x * 32;

    // ----- Phase 1: LayerNorm -> swizzled bf16 A tile [32][512] -----
    const float4* x4 = (const float4*)x;
    float4 g0 = ((const float4*)ln_g)[l];
    float4 g1 = ((const float4*)ln_g)[l + 64];
    float4 q0 = ((const float4*)ln_b)[l];
    float4 q1 = ((const float4*)ln_b)[l + 64];
    #pragma unroll 4
    for (int i = 0; i < 8; ++i) {
        int r = w * 8 + i;
        float4 xa = x4[(size_t)(row_base + r) * 128 + l];
        float4 xb = x4[(size_t)(row_base + r) * 128 + 64 + l];
        float s1 = xa.x + xa.y + xa.z + xa.w + xb.x + xb.y + xb.z + xb.w;
        float s2 = xa.x*xa.x + xa.y*xa.y + xa.z*xa.z + xa.w*xa.w
                 + xb.x*xb.x + xb.y*xb.y + xb.z*xb.z + xb.w*xb.w;
        #pragma unroll
        for (int m = 1; m < 64; m <<= 1) {
            s1 += __shfl_xor(s1, m);
            s2 += __shfl_xor(s2, m);
        }
        float mu = s1 * (1.f / 512.f);
        float var = s2 * (1.f / 512.f) - mu * mu;
        float rs = rsqrtf(var + 1e-5f);
        float ya0 = (xa.x - mu) * rs * g0.x + q0.x;
        float ya1 = (xa.y - mu) * rs * g0.y + q0.y;
        float ya2 = (xa.z - mu) * rs * g0.z + q0.z;
        float ya3 = (xa.w - mu) * rs * g0.w + q0.w;
        float yb0 = (xb.x - mu) * rs * g1.x + q1.x;
        float yb1 = (xb.y - mu) * rs * g1.y + q1.y;
        float yb2 = (xb.z - mu) * rs * g1.z + q1.z;
        float yb3 = (xb.w - mu) * rs * g1.w + q1.w;
        unsigned long long pa =
            (unsigned long long)f2bf(ya0) | ((unsigned long long)f2bf(ya1) << 16) |
            ((unsigned long long)f2bf(ya2) << 32) | ((unsigned long long)f2bf(ya3) << 48);
        unsigned long long pb =
            (unsigned long long)f2bf(yb0) | ((unsigned long long)f2bf(yb1) << 16) |
            ((unsigned long long)f2bf(yb2) << 32) | ((unsigned long long)f2bf(yb3) << 48);
        int sw = (r & 7) << 4;
        *(unsigned long long*)(smem + ((r * 1024 + l * 8) ^ sw)) = pa;
        *(unsigned long long*)(smem + ((r * 1024 + 512 + l * 8) ^ sw)) = pb;
    }
    __syncthreads();

    // ----- Phase 2: MFMA GEMM [32 x 512] @ [512 x 288] -----
    int cnt = (w < 2) ? 5 : 4;
    int nts[5];
    #pragma unroll
    for (int i = 0; i < 4; ++i) nts[i] = w + i * 4;
    nts[4] = 16 + w;

    const bfrag_t* wf = (const bfrag_t*)(ws + WFRAG_OFF);
    int swa = (l & 7) << 4;
    int ab0 = lane_lo * 1024 + (lane_hi << 4);
    int ab1 = (16 + lane_lo) * 1024 + (lane_hi << 4);

    floatx4 acc[5][2];
    #pragma unroll
    for (int i = 0; i < 5; ++i)
        #pragma unroll
        for (int mt = 0; mt < 2; ++mt)
            acc[i][mt] = (floatx4){0.f, 0.f, 0.f, 0.f};

    bfrag_t acur0, acur1, anxt0, anxt1, bcur[5], bnxt[5];
    acur0 = *(const bfrag_t*)(smem + (ab0 ^ swa));
    acur1 = *(const bfrag_t*)(smem + (ab1 ^ swa));
    #pragma unroll
    for (int i = 0; i < 5; ++i)
        if (i < cnt) bcur[i] = wf[(0 * 18 + nts[i]) * 64 + l];

    for (int kt = 0; kt < 16; ++kt) {
        if (kt < 15) {
            int ko = (kt + 1) * 64;
            anxt0 = *(const bfrag_t*)(smem + ((ab0 + ko) ^ swa));
            anxt1 = *(const bfrag_t*)(smem + ((ab1 + ko) ^ swa));
            #pragma unroll
            for (int i = 0; i < 5; ++i)
                if (i < cnt) bnxt[i] = wf[((kt + 1) * 18 + nts[i]) * 64 + l];
        }
        #pragma unroll
        for (int i = 0; i < 5; ++i) {
            if (i < cnt) {
                acc[i][0] = __builtin_amdgcn_mfma_f32_16x16x32_bf16(acur0, bcur[i], acc[i][0], 0, 0, 0);
                acc[i][1] = __builtin_amdgcn_mfma_f32_16x16x32_bf16(acur1, bcur[i], acc[i][1], 0, 0, 0);
            }
        }
        acur0 = anxt0; acur1 = anxt1;
        #pragma unroll
        for (int i = 0; i < 5; ++i)
            if (i < cnt) bcur[i] = bnxt[i];
    }
    __syncthreads();   // A tile dead

    // ----- Phase 3: epilogue -> xp (bf16), u (bf16), scores (f32) -----
    {
        const float* bu = (const float*)(ws + BU_OFF);
        const float* bs = (const float*)(ws + BS_OFF);
        unsigned short* xp_l = (unsigned short*)(smem + A_XP);
        unsigned short* u_l  = (unsigned short*)(smem + A_U);
        float* sc_l = (float*)(smem + A_SC);
        #pragma unroll
        for (int i = 0; i < 5; ++i) {
            if (i < cnt) {
                int n = nts[i] * 16 + lane_lo;
                #pragma unroll
                for (int mt = 0; mt < 2; ++mt) {
                    #pragma unroll
                    for (int r4 = 0; r4 < 4; ++r4) {
                        int row = mt * 16 + lane_hi * 4 + r4;
                        float v = acc[i][mt][r4];
                        if (i < 2)      xp_l[row * 128 + n] = f2bf(v + b_in[n]);
                        else if (i < 4) u_l[row * 128 + (n - 128)] = f2bf(v + bu[n - 128]);
                        else            sc_l[row * 32 + (n - 256)] = v + bs[n - 256];
                    }
                }
            }
        }
    }
    __syncthreads();

    // ----- issue xp/u materialize writes (overlap with softmax) -----
    {
        const uint4* xpl4 = (const uint4*)(smem + A_XP);
        const uint4* ul4  = (const uint4*)(smem + A_U);
        uint4* xpg4 = (uint4*)(ws + XP_G_OFF) + (size_t)blockIdx.x * 512;
        uint4* ug4  = (uint4*)(ws + U_G_OFF)  + (size_t)blockIdx.x * 512;
        #pragma unroll
        for (int q = 0; q < 2; ++q) {
            int idx = q * 256 + tid;
            xpg4[idx] = xpl4[idx];
            ug4[idx]  = ul4[idx];
        }
    }

    // ----- Phase 4: softmax (8 rows/wave), write PR frag + linear probs -----
    #pragma unroll
    for (int i = 0; i < 8; ++i) {
        int r = w * 8 + i;
        int s = l & 31;
        float sc = *(const float*)(smem + A_SC + (r * 32 + s) * 4);
        float mx = sc;
        #pragma unroll
        for (int m = 1; m < 32; m <<= 1) mx = fmaxf(mx, __shfl_xor(mx, m));
        float e = __expf(sc - mx);
        float sum = e;
        #pragma unroll
        for (int m = 1; m < 32; m <<= 1) sum += __shfl_xor(sum, m);
        float p = e * __builtin_amdgcn_rcpf(sum);
        if (l < 32) {
            unsigned short pb = f2bf(p);
            // A-frag for read-GEMM: mt=r>>4, lane=(r&15)+16*(s>>3), j=s&7
            *(unsigned short*)(smem + A_PR +
                (((r >> 4) * 64 + ((r & 15) + 16 * (s >> 3))) * 8 + (s & 7)) * 2) = pb;
            *(unsigned short*)(smem + A_PRL + (r * 32 + s) * 2) = pb;
        }
    }
    __syncthreads();

    // ----- Phase 5: read-GEMM probs@mem -> rc (LDS) -----
    {
        bfrag_t pa0 = *(const bfrag_t*)(smem + A_PR + l * 16);
        bfrag_t pa1 = *(const bfrag_t*)(smem + A_PR + 1024 + l * 16);
        const bfrag_t* mf = (const bfrag_t*)(ws + MEMFRAG_OFF);
        #pragma unroll
        for (int j = 0; j < 2; ++j) {
            int nt = 2 * w + j;
            bfrag_t bm = mf[nt * 64 + l];
            floatx4 r0 = (floatx4){0.f, 0.f, 0.f, 0.f};
            floatx4 r1 = (floatx4){0.f, 0.f, 0.f, 0.f};
            r0 = __builtin_amdgcn_mfma_f32_16x16x32_bf16(pa0, bm, r0, 0, 0, 0);
            r1 = __builtin_amdgcn_mfma_f32_16x16x32_bf16(pa1, bm, r1, 0, 0, 0);
            int nc = nt * 16 + lane_lo;
            #pragma unroll
            for (int r4 = 0; r4 < 4; ++r4) {
                int row = lane_hi * 4 + r4;
                *(float*)(smem + A_RC + (row * 128 + nc) * 4) = r0[r4];
                *(float*)(smem + A_RC + ((row + 16) * 128 + nc) * 4) = r1[r4];
            }
        }
    }
    __syncthreads();

    // ----- Phase 6: rc writeback + probs materialize -----
    {
        const float4* rc4 = (const float4*)(smem + A_RC);
        float4* out4 = (float4*)out;
        #pragma unroll
        for (int q = 0; q < 4; ++q) {
            int idx = q * 256 + tid;
            int row = idx >> 5, c4 = idx & 31;
            out4[(size_t)(row_base + row) * 32 + c4] = rc4[idx];
        }
        if (tid < 128) {
            uint4* prg4 = (uint4*)(ws + PR_G_OFF) + (size_t)blockIdx.x * 128;
            prg4[tid] = ((const uint4*)(smem + A_PRL))[tid];
        }
    }
}

// ================= kernel B: gate sigmoids + write-path accumulation =================
__global__ __launch_bounds__(256, 4) void gate_kernel(
    unsigned char* __restrict__ ws)
{
    __shared__ char smem[18432] __attribute__((aligned(16)));
    // probs [32][32] bf16 @0 (2KB); xp [32][128] bf16 @2048 (8KB); u @10240 (8KB)
    int tid = threadIdx.x;
    int w = tid >> 6, l = tid & 63;

    {
        uint4* pl = (uint4*)smem;
        const uint4* prg4 = (const uint4*)(ws + PR_G_OFF) + (size_t)blockIdx.x * 128;
        if (tid < 128) pl[tid] = prg4[tid];
        uint4* xpl = (uint4*)(smem + 2048);
        uint4* ul  = (uint4*)(smem + 10240);
        const uint4* xpg4 = (const uint4*)(ws + XP_G_OFF) + (size_t)blockIdx.x * 512;
        const uint4* ug4  = (const uint4*)(ws + U_G_OFF)  + (size_t)blockIdx.x * 512;
        #pragma unroll
        for (int q = 0; q < 2; ++q) {
            int idx = q * 256 + tid;
            xpl[idx] = xpg4[idx];
            ul[idx]  = ug4[idx];
        }
    }
    __syncthreads();

    const unsigned short* p_l  = (const unsigned short*)smem;
    const unsigned short* xp_l = (const unsigned short*)(smem + 2048);
    const unsigned short* u_l  = (const unsigned short*)(smem + 10240);

    int sbase = w * 8;
    const float* gb = (const float*)(ws + GB_OFF);
    float gbr0[8], gbr1[8];
    float aw0[8], aw1[8], ag0[8], ag1[8];
    #pragma unroll
    for (int si = 0; si < 8; ++si) {
        gbr0[si] = gb[(sbase + si) * 128 + l];
        gbr1[si] = gb[(sbase + si) * 128 + l + 64];
        aw0[si] = aw1[si] = ag0[si] = ag1[si] = 0.f;
    }
    for (int r = 0; r < 32; ++r) {
        float uv0 = bf2f(u_l[r * 128 + l]);
        float uv1 = bf2f(u_l[r * 128 + l + 64]);
        float xv0 = bf2f(xp_l[r * 128 + l]);
        float xv1 = bf2f(xp_l[r * 128 + l + 64]);
        #pragma unroll
        for (int si = 0; si < 8; ++si) {
            float p = bf2f(p_l[r * 32 + sbase + si]);
            ag0[si] += sigm(gbr0[si] + uv0);
            ag1[si] += sigm(gbr1[si] + uv1);
            aw0[si] += p * xv0;
            aw1[si] += p * xv1;
        }
    }
    float* accw = (float*)(ws + ACC_OFF + (size_t)(blockIdx.x & 63) * 32768);
    float* accg = accw + 4096;
    #pragma unroll
    for (int si = 0; si < 8; ++si) {
        __hip_atomic_fetch_add(&accw[(sbase + si) * 128 + l],      aw0[si], __ATOMIC_RELAXED, __HIP_MEMORY_SCOPE_AGENT);
        __hip_atomic_fetch_add(&accw[(sbase + si) * 128 + l + 64], aw1[si], __ATOMIC_RELAXED, __HIP_MEMORY_SCOPE_AGENT);
        __hip_atomic_fetch_add(&accg[(sbase + si) * 128 + l],      ag0[si], __ATOMIC_RELAXED, __HIP_MEMORY_SCOPE_AGENT);
        __hip_atomic_fetch_add(&accg[(sbase + si) * 128 + l + 64], ag1[si], __ATOMIC_RELAXED, __HIP_MEMORY_SCOPE_AGENT);
    }
}

// ---------------- finalize: reduce 64 copies -> new_memory ----------------
__global__ __launch_bounds__(512) void fin_kernel(
    const float* __restrict__ memv, const unsigned char* __restrict__ ws,
    float* __restrict__ out2)
{
    int i = blockIdx.x * 512 + threadIdx.x;   // 8 blocks x 512 = 4096
    const float* base = (const float*)(ws + ACC_OFF);
    float aw = 0.f, ag = 0.f;
    #pragma unroll 8
    for (int c = 0; c < 64; ++c) {
        aw += base[c * 8192 + i];
        ag += base[c * 8192 + 4096 + i];
    }
    ag *= (1.f / 16384.f);
    aw *= (1.f / 16384.f);
    out2[i] = memv[i] * (1.f - ag) + aw * ag;
}

// ================= legacy monolithic fallback (R3) =================
__global__ __launch_bounds__(256, 4) void legacy_main(
    const float* __restrict__ x,
    const float* __restrict__ ln_g, const float* __restrict__ ln_b,
    const float* __restrict__ b_in, unsigned char* __restrict__ ws,
    float* __restrict__ out, int copy_mask)
{
    __shared__ char smem[L_LDS] __attribute__((aligned(16)));
    int tid = threadIdx.x;
    int w = tid >> 6, l = tid & 63;
    int lane_lo = l & 15, lane_hi = l >> 4;
    int row_base = blockIdx.x * 16;
    {
        float* z1 = (float*)(smem + L_XPF);
        #pragma unroll
        for (int i = 0; i < 8; ++i) z1[tid + i * 256] = 0.f;
        float* z2 = (float*)(smem + L_PRT);
        #pragma unroll
        for (int i = 0; i < 2; ++i) z2[tid + i * 256] = 0.f;
    }
    const float4* x4 = (const float4*)x;
    float4 g0 = ((const float4*)ln_g)[l];
    float4 g1 = ((const float4*)ln_g)[l + 64];
    float4 q0 = ((const float4*)ln_b)[l];
    float4 q1 = ((const float4*)ln_b)[l + 64];
    #pragma unroll
    for (int i = 0; i < 4; ++i) {
        int r = w * 4 + i;
        float4 xa = x4[(size_t)(row_base + r) * 128 + l];
        float4 xb = x4[(size_t)(row_base + r) * 128 + 64 + l];
        float s1 = xa.x + xa.y + xa.z + xa.w + xb.x + xb.y + xb.z + xb.w;
        float s2 = xa.x*xa.x + xa.y*xa.y + xa.z*xa.z + xa.w*xa.w
                 + xb.x*xb.x + xb.y*xb.y + xb.z*xb.z + xb.w*xb.w;
        #pragma unroll
        for (int m = 1; m < 64; m <<= 1) {
            s1 += __shfl_xor(s1, m);
            s2 += __shfl_xor(s2, m);
        }
        float mu = s1 * (1.f / 512.f);
        float var = s2 * (1.f / 512.f) - mu * mu;
        float rs = rsqrtf(var + 1e-5f);
        float ya0 = (xa.x - mu) * rs * g0.x + q0.x;
        float ya1 = (xa.y - mu) * rs * g0.y + q0.y;
        float ya2 = (xa.z - mu) * rs * g0.z + q0.z;
        float ya3 = (xa.w - mu) * rs * g0.w + q0.w;
        float yb0 = (xb.x - mu) * rs * g1.x + q1.x;
        float yb1 = (xb.y - mu) * rs * g1.y + q1.y;
        float yb2 = (xb.z - mu) * rs * g1.z + q1.z;
        float yb3 = (xb.w - mu) * rs * g1.w + q1.w;
        unsigned long long pa =
            (unsigned long long)f2bf(ya0) | ((unsigned long long)f2bf(ya1) << 16) |
            ((unsigned long long)f2bf(ya2) << 32) | ((unsigned long long)f2bf(ya3) << 48);
        unsigned long long pb =
            (unsigned long long)f2bf(yb0) | ((unsigned long long)f2bf(yb1) << 16) |
            ((unsigned long long)f2bf(yb2) << 32) | ((unsigned long long)f2bf(yb3) << 48);
        int sw = (r & 7) << 4;
        *(unsigned long long*)(smem + ((r * 1024 + l * 8) ^ sw)) = pa;
        *(unsigned long long*)(smem + ((r * 1024 + 512 + l * 8) ^ sw)) = pb;
    }
    __syncthreads();
    int cnt = (w < 2) ? 5 : 4;
    int nts[5];
    #pragma unroll
    for (int i = 0; i < 4; ++i) nts[i] = w + i * 4;
    nts[4] = 16 + w;
    const bfrag_t* wf = (const bfrag_t*)(ws + WFRAG_OFF);
    int swa = (l & 7) << 4;
    int ab0 = lane_lo * 1024 + (lane_hi << 4);
    floatx4 acc[5];
    #pragma unroll
    for (int i = 0; i < 5; ++i) acc[i] = (floatx4){0.f, 0.f, 0.f, 0.f};
    bfrag_t acur, anxt, bcur[5], bnxt[5];
    acur = *(const bfrag_t*)(smem + (ab0 ^ swa));
    #pragma unroll
    for (int i = 0; i < 5; ++i)
        if (i < cnt) bcur[i] = wf[(0 * 18 + nts[i]) * 64 + l];
    for (int kt = 0; kt < 16; ++kt) {
        if (kt < 15) {
            int ko = (kt + 1) * 64;
            anxt = *(const bfrag_t*)(smem + ((ab0 + ko) ^ swa));
            #pragma unroll
            for (int i = 0; i < 5; ++i)
                if (i < cnt) bnxt[i] = wf[((kt + 1) * 18 + nts[i]) * 64 + l];
        }
        #pragma unroll
        for (int i = 0; i < 5; ++i)
            if (i < cnt)
                acc[i] = __builtin_amdgcn_mfma_f32_16x16x32_bf16(acur, bcur[i], acc[i], 0, 0, 0);
        acur = anxt;
        #pragma unroll
        for (int i = 0; i < 5; ++i)
            if (i < cnt) bcur[i] = bnxt[i];
    }
    __syncthreads();
    {
        const float* bu = (const float*)(ws + BU_OFF);
        const float* bs = (const float*)(ws + BS_OFF);
        #pragma unroll
        for (int i = 0; i < 5; ++i) {
            if (i < cnt) {
                int n = nts[i] * 16 + lane_lo;
                #pragma unroll
                for (int r4 = 0; r4 < 4; ++r4) {
                    int row = lane_hi * 4 + r4;
                    float v = acc[i][r4];
                    if (i < 2) {
                        float val = v + b_in[n];
                        int addr = L_XPF +
                            (((n >> 4) * 64 + ((n & 15) | ((row >> 3) << 4))) * 8
                             + (row & 7)) * 2;
                        *(unsigned short*)(smem + addr) = f2bf(val);
                    } else if (i < 4) {
                        int d = n - 128;
                        *(float*)(smem + L_U + (row * 128 + d) * 4) = v + bu[d];
                    } else {
                        int s = n - 256;
                        *(float*)(smem + L_SC + (row * 32 + s) * 4) = v + bs[s];
                    }
                }
            }
        }
    }
    __syncthreads();
    #pragma unroll
    for (int i = 0; i < 4; ++i) {
        int r = w * 4 + i;
        int s = l & 31;
        float sc = *(const float*)(smem + L_SC + (r * 32 + s) * 4);
        float mx = sc;
        #pragma unroll
        for (int m = 1; m < 32; m <<= 1) mx = fmaxf(mx, __shfl_xor(mx, m));
        float e = __expf(sc - mx);
        float sum = e;
        #pragma unroll
        for (int m = 1; m < 32; m <<= 1) sum += __shfl_xor(sum, m);
        float p = e * __builtin_amdgcn_rcpf(sum);
        if (l < 32) {
            unsigned short pb = f2bf(p);
            *(unsigned short*)(smem + L_PR + (((s >> 3) * 16 + r) * 8 + (s & 7)) * 2) = pb;
            *(unsigned short*)(smem + L_PRT +
                (((s >> 4) * 64 + ((s & 15) | ((r >> 3) << 4))) * 8 + (r & 7)) * 2) = pb;
        }
    }
    __syncthreads();
    float* accw = (float*)(ws + ACC_OFF + (size_t)(blockIdx.x & copy_mask) * 32768);
    float* accg = accw + 4096;
    {
        bfrag_t pa  = *(const bfrag_t*)(smem + L_PR + l * 16);
        bfrag_t pat0 = *(const bfrag_t*)(smem + L_PRT + l * 16);
        bfrag_t pat1 = *(const bfrag_t*)(smem + L_PRT + 1024 + l * 16);
        const bfrag_t* mf = (const bfrag_t*)(ws + MEMFRAG_OFF);
        bfrag_t bm[2], bx[2];
        #pragma unroll
        for (int j = 0; j < 2; ++j) {
            int nt = 2 * w + j;
            bm[j] = mf[nt * 64 + l];
            bx[j] = *(const bfrag_t*)(smem + L_XPF + (nt * 64 + l) * 16);
        }
        floatx4 rca[2], wa[2][2];
        #pragma unroll
        for (int j = 0; j < 2; ++j) {
            rca[j]  = (floatx4){0.f, 0.f, 0.f, 0.f};
            rca[j]  = __builtin_amdgcn_mfma_f32_16x16x32_bf16(pa, bm[j], rca[j], 0, 0, 0);
            wa[j][0] = (floatx4){0.f, 0.f, 0.f, 0.f};
            wa[j][1] = (floatx4){0.f, 0.f, 0.f, 0.f};
            wa[j][0] = __builtin_amdgcn_mfma_f32_16x16x32_bf16(pat0, bx[j], wa[j][0], 0, 0, 0);
            wa[j][1] = __builtin_amdgcn_mfma_f32_16x16x32_bf16(pat1, bx[j], wa[j][1], 0, 0, 0);
        }
        #pragma unroll
        for (int j = 0; j < 2; ++j) {
            int nc = (2 * w + j) * 16 + lane_lo;
            #pragma unroll
            for (int r4 = 0; r4 < 4; ++r4) {
                int row = lane_hi * 4 + r4;
                *(float*)(smem + L_RC + (row * 128 + nc) * 4) = rca[j][r4];
            }
            #pragma unroll
            for (int mt = 0; mt < 2; ++mt) {
                #pragma unroll
                for (int r4 = 0; r4 < 4; ++r4) {
                    int s = mt * 16 + lane_hi * 4 + r4;
                    __hip_atomic_fetch_add(&accw[s * 128 + nc], wa[j][mt][r4],
                                           __ATOMIC_RELAXED, __HIP_MEMORY_SCOPE_AGENT);
                }
            }
        }
    }
    __syncthreads();
    {
        const float4* rc4 = (const float4*)(smem + L_RC);
        float4* out4 = (float4*)out;
        #pragma unroll
        for (int q = 0; q < 2; ++q) {
            int idx = q * 256 + tid;
            int row = idx >> 5, c4 = idx & 31;
            out4[(size_t)(row_base + row) * 32 + c4] = rc4[idx];
        }
    }
    {
        int sbase = w * 8;
        const float* gb = (const float*)(ws + GB_OFF);
        float gbr0[8], gbr1[8], ag0[8], ag1[8];
        #pragma unroll
        for (int si = 0; si < 8; ++si) {
            gbr0[si] = gb[(sbase + si) * 128 + l];
            gbr1[si] = gb[(sbase + si) * 128 + l + 64];
            ag0[si] = 0.f; ag1[si] = 0.f;
        }
        for (int r = 0; r < 16; ++r) {
            float uv0 = *(const float*)(smem + L_U + (r * 128 + l) * 4);
            float uv1 = *(const float*)(smem + L_U + (r * 128 + l + 64) * 4);
            #pragma unroll
            for (int si = 0; si < 8; ++si) {
                ag0[si] += sigm(gbr0[si] + uv0);
                ag1[si] += sigm(gbr1[si] + uv1);
            }
        }
        #pragma unroll
        for (int si = 0; si < 8; ++si) {
            __hip_atomic_fetch_add(&accg[(sbase + si) * 128 + l],      ag0[si],
                                   __ATOMIC_RELAXED, __HIP_MEMORY_SCOPE_AGENT);
            __hip_atomic_fetch_add(&accg[(sbase + si) * 128 + l + 64], ag1[si],
                                   __ATOMIC_RELAXED, __HIP_MEMORY_SCOPE_AGENT);
        }
    }
}

__global__ __launch_bounds__(128) void legacy_fin(
    const float* __restrict__ memv, const unsigned char* __restrict__ ws,
    float* __restrict__ out2, int ncopy)
{
    int i = blockIdx.x * 128 + threadIdx.x;
    const float* base = (const float*)(ws + ACC_OFF);
    float aw = 0.f, ag = 0.f;
    #pragma unroll 8
    for (int c = 0; c < ncopy; ++c) {
        aw += base[c * 8192 + i];
        ag += base[c * 8192 + 4096 + i];
    }
    ag *= (1.f / 16384.f);
    aw *= (1.f / 16384.f);
    out2[i] = memv[i] * (1.f - ag) + aw * ag;
}

// ---------------- launcher ----------------
extern "C" void kernel_launch(void* const* d_in, const int* in_sizes, int n_in,
                              void* d_out, int out_size, void* d_ws, size_t ws_size,
                              hipStream_t stream)
{
    (void)in_sizes; (void)n_in; (void)out_size;
    const float* x      = (const float*)d_in[0];
    const float* memv   = (const float*)d_in[1];
    const float* ln_g   = (const float*)d_in[2];
    const float* ln_b   = (const float*)d_in[3];
    const float* w_in   = (const float*)d_in[4];
    const float* b_in   = (const float*)d_in[5];
    const float* w_gate = (const float*)d_in[6];
    const float* b_gate = (const float*)d_in[7];
    float* out = (float*)d_out;
    unsigned char* ws = (unsigned char*)d_ws;

    if (ws_size >= (size_t)WS_NEED) {
        hipLaunchKernelGGL(prep_kernel, dim3(289), dim3(256), 0, stream,
                           memv, w_in, b_in, w_gate, b_gate, ws, 64);
        hipLaunchKernelGGL(gemm_kernel, dim3(512), dim3(256), 0, stream,
                           x, ln_g, ln_b, b_in, ws, out);
        hipLaunchKernelGGL(gate_kernel, dim3(512), dim3(256), 0, stream, ws);
        hipLaunchKernelGGL(fin_kernel, dim3(8), dim3(512), 0, stream,
                           memv, ws, out + 2097152);
    } else {
        int ncopy = (ws_size >= (size_t)ACC_OFF + 64 * 32768) ? 64 : 32;
        hipLaunchKernelGGL(prep_kernel, dim3(289), dim3(256), 0, stream,
                           memv, w_in, b_in, w_gate, b_gate, ws, ncopy);
        hipLaunchKernelGGL(legacy_main, dim3(1024), dim3(256), 0, stream,
                           x, ln_g, ln_b, b_in, ws, out, ncopy - 1);
        hipLaunchKernelGGL(legacy_fin, dim3(32), dim3(128), 0, stream,
                           memv, ws, out + 2097152, ncopy);
    }
}

// Round 7
// 49.296 us; speedup vs baseline: 1.4046x; 1.4046x over previous
//
#include <hip/hip_runtime.h>
#include <stdint.h>

typedef __attribute__((ext_vector_type(8))) short bfrag_t;   // 8 bf16
typedef __attribute__((ext_vector_type(4))) float floatx4;   // MFMA acc

// ---------------- ws layout (bytes) ----------------
#define WFRAG_OFF   0            // bf16 [16kt][18nt][64lane][8j] = 294912
#define GB_OFF      294912       // f32 [32][128]
#define BU_OFF      311296       // f32 [128]
#define BS_OFF      311808       // f32 [32]
#define MEMFRAG_OFF 311936       // bf16 frag [8nt][64][8] = 8192
#define ACC_OFF     327680       // ncopy x (accw[4096] | accg[4096]) f32

// ---------------- main LDS layout (bytes) ----------------
// A-tile [32r][1024B] = 32768 @0 during phases 1-2; overlaid after:
#define M_XPF   0        // bf16 B-frag [8nt][64][8] (k=rows) = 8192
#define M_U     8192     // f32 [32][128] = 16384
#define M_SC    24576    // f32 [32][32] = 4096
#define M_PR    28672    // bf16 A-frag [2mt][64][8] (probs, k=s) = 2048
#define M_PRT   30720    // bf16 A-frag [2mt][64][8] (probsT, k=r) = 2048
#define M_RC    32768    // f32 [32][128] = 16384
#define M_LDS   49152

__device__ __forceinline__ unsigned short f2bf(float f) {
    unsigned u = __float_as_uint(f);
    u += 0x7fffu + ((u >> 16) & 1u);
    return (unsigned short)(u >> 16);
}
__device__ __forceinline__ float sigm(float v) {
    return __builtin_amdgcn_rcpf(1.0f + __expf(-v));
}
__device__ __forceinline__ void writefrag(unsigned short* wf, int k, int n, float v) {
    int kt = k >> 5, kk = k & 31;
    int lane = (n & 15) | ((kk >> 3) << 4);
    wf[(((kt * 18) + (n >> 4)) * 64 + lane) * 8 + (kk & 7)] = f2bf(v);
}

// ---------------- prep: frag weights, gate base, biases, mem frags, zero ----------------
__global__ __launch_bounds__(256) void prep_kernel(
    const float* __restrict__ memv, const float* __restrict__ w_in,
    const float* __restrict__ b_in, const float* __restrict__ w_gate,
    const float* __restrict__ b_gate, unsigned char* __restrict__ ws, int ncopy)
{
    int bid = blockIdx.x, t = threadIdx.x;
    unsigned short* wfrag = (unsigned short*)(ws + WFRAG_OFF);
    const float* wg2 = w_gate + 128 * 128;

    if (bid < 256) {
        __shared__ float wrow[2][128];
        int k0 = bid * 2;
        wrow[t >> 7][t & 127] = w_in[(size_t)(k0 + (t >> 7)) * 128 + (t & 127)];
        __syncthreads();
        for (int kl = 0; kl < 2; ++kl) {
            int k = k0 + kl;
            float v;
            if (t < 128) {
                v = wrow[kl][t];
            } else {
                int d = t - 128;
                float acc = 0.f;
                #pragma unroll 16
                for (int j = 0; j < 128; ++j) acc += wrow[kl][j] * wg2[j * 128 + d];
                v = acc;
            }
            writefrag(wfrag, k, t, v);
            if (t < 32) {
                float acc = 0.f;
                #pragma unroll 16
                for (int d = 0; d < 128; ++d) acc += wrow[kl][d] * memv[t * 128 + d];
                writefrag(wfrag, k, 256 + t, acc);
            }
        }
    } else if (bid < 272) {
        int idx = (bid - 256) * 256 + t;
        int s = idx >> 7, d = idx & 127;
        float acc = b_gate[d];
        #pragma unroll 16
        for (int k = 0; k < 128; ++k) acc += memv[s * 128 + k] * w_gate[k * 128 + d];
        ((float*)(ws + GB_OFF))[idx] = acc;
    } else if (bid == 272) {
        if (t < 128) {
            float acc = 0.f;
            #pragma unroll 16
            for (int j = 0; j < 128; ++j) acc += b_in[j] * wg2[j * 128 + t];
            ((float*)(ws + BU_OFF))[t] = acc;
        }
        if (t < 32) {
            float acc = 0.f;
            #pragma unroll 16
            for (int d = 0; d < 128; ++d) acc += b_in[d] * memv[t * 128 + d];
            ((float*)(ws + BS_OFF))[t] = acc;
        }
        unsigned short* mfr = (unsigned short*)(ws + MEMFRAG_OFF);
        for (int idx = t; idx < 4096; idx += 256) {
            int s = idx >> 7, d = idx & 127;
            mfr[((d >> 4) * 64 + ((d & 15) | (((s >> 3) & 3) << 4))) * 8 + (s & 7)]
                = f2bf(memv[idx]);
        }
    } else {
        int zb = bid - 273;    // 16 blocks
        float4* dst = (float4*)(ws + ACC_OFF + (size_t)zb * ncopy * 2048);
        int n4 = ncopy * 128;
        for (int i = t; i < n4; i += 256) dst[i] = (float4){0.f, 0.f, 0.f, 0.f};
    }
}

// ---------------- main: 512 blocks x 512 threads, 32 rows/block ----------------
__global__ __launch_bounds__(512, 4) void main_kernel(
    const float* __restrict__ x,
    const float* __restrict__ ln_g, const float* __restrict__ ln_b,
    const float* __restrict__ b_in, unsigned char* __restrict__ ws,
    float* __restrict__ out, int copy_mask)
{
    __shared__ char smem[M_LDS] __attribute__((aligned(16)));

    int tid = threadIdx.x;
    int w = tid >> 6, l = tid & 63;          // 8 waves
    int lane_lo = l & 15, lane_hi = l >> 4;
    int row_base = blockIdx.x * 32;

    // ===== Phase 1: LayerNorm -> swizzled bf16 A tile [32][512], 4 rows/wave =====
    const float4* x4 = (const float4*)x;
    float4 g0 = ((const float4*)ln_g)[l];
    float4 g1 = ((const float4*)ln_g)[l + 64];
    float4 q0 = ((const float4*)ln_b)[l];
    float4 q1 = ((const float4*)ln_b)[l + 64];
    #pragma unroll
    for (int i = 0; i < 4; ++i) {
        int r = w * 4 + i;
        float4 xa = x4[(size_t)(row_base + r) * 128 + l];
        float4 xb = x4[(size_t)(row_base + r) * 128 + 64 + l];
        float s1 = xa.x + xa.y + xa.z + xa.w + xb.x + xb.y + xb.z + xb.w;
        float s2 = xa.x*xa.x + xa.y*xa.y + xa.z*xa.z + xa.w*xa.w
                 + xb.x*xb.x + xb.y*xb.y + xb.z*xb.z + xb.w*xb.w;
        #pragma unroll
        for (int m = 1; m < 64; m <<= 1) {
            s1 += __shfl_xor(s1, m);
            s2 += __shfl_xor(s2, m);
        }
        float mu = s1 * (1.f / 512.f);
        float var = s2 * (1.f / 512.f) - mu * mu;
        float rs = rsqrtf(var + 1e-5f);
        float ya0 = (xa.x - mu) * rs * g0.x + q0.x;
        float ya1 = (xa.y - mu) * rs * g0.y + q0.y;
        float ya2 = (xa.z - mu) * rs * g0.z + q0.z;
        float ya3 = (xa.w - mu) * rs * g0.w + q0.w;
        float yb0 = (xb.x - mu) * rs * g1.x + q1.x;
        float yb1 = (xb.y - mu) * rs * g1.y + q1.y;
        float yb2 = (xb.z - mu) * rs * g1.z + q1.z;
        float yb3 = (xb.w - mu) * rs * g1.w + q1.w;
        unsigned long long pa =
            (unsigned long long)f2bf(ya0) | ((unsigned long long)f2bf(ya1) << 16) |
            ((unsigned long long)f2bf(ya2) << 32) | ((unsigned long long)f2bf(ya3) << 48);
        unsigned long long pb =
            (unsigned long long)f2bf(yb0) | ((unsigned long long)f2bf(yb1) << 16) |
            ((unsigned long long)f2bf(yb2) << 32) | ((unsigned long long)f2bf(yb3) << 48);
        int sw = (r & 7) << 4;
        *(unsigned long long*)(smem + ((r * 1024 + l * 8) ^ sw)) = pa;
        *(unsigned long long*)(smem + ((r * 1024 + 512 + l * 8) ^ sw)) = pb;
    }
    __syncthreads();

    // ===== Phase 2: MFMA GEMM [32 x 512] @ [512 x 288] =====
    // wave w owns n-tiles {w, w+8} (+16+w if w<2), BOTH m-tiles
    int nf = (w < 2) ? 3 : 2;
    int nts[3] = {w, w + 8, 16 + w};

    const bfrag_t* wf = (const bfrag_t*)(ws + WFRAG_OFF);
    int swa = (l & 7) << 4;
    int ab0 = lane_lo * 1024 + (lane_hi << 4);
    int ab1 = (16 + lane_lo) * 1024 + (lane_hi << 4);

    floatx4 acc[3][2];
    #pragma unroll
    for (int i = 0; i < 3; ++i)
        #pragma unroll
        for (int mt = 0; mt < 2; ++mt)
            acc[i][mt] = (floatx4){0.f, 0.f, 0.f, 0.f};

    bfrag_t acur0, acur1, anxt0, anxt1, bcur[3], bnxt[3];
    acur0 = *(const bfrag_t*)(smem + (ab0 ^ swa));
    acur1 = *(const bfrag_t*)(smem + (ab1 ^ swa));
    #pragma unroll
    for (int i = 0; i < 3; ++i)
        if (i < nf) bcur[i] = wf[(0 * 18 + nts[i]) * 64 + l];

    for (int kt = 0; kt < 16; ++kt) {
        if (kt < 15) {
            int ko = (kt + 1) * 64;
            anxt0 = *(const bfrag_t*)(smem + ((ab0 + ko) ^ swa));
            anxt1 = *(const bfrag_t*)(smem + ((ab1 + ko) ^ swa));
            #pragma unroll
            for (int i = 0; i < 3; ++i)
                if (i < nf) bnxt[i] = wf[((kt + 1) * 18 + nts[i]) * 64 + l];
        }
        #pragma unroll
        for (int i = 0; i < 3; ++i) {
            if (i < nf) {
                acc[i][0] = __builtin_amdgcn_mfma_f32_16x16x32_bf16(acur0, bcur[i], acc[i][0], 0, 0, 0);
                acc[i][1] = __builtin_amdgcn_mfma_f32_16x16x32_bf16(acur1, bcur[i], acc[i][1], 0, 0, 0);
            }
        }
        acur0 = anxt0; acur1 = anxt1;
        #pragma unroll
        for (int i = 0; i < 3; ++i)
            if (i < nf) bcur[i] = bnxt[i];
    }
    __syncthreads();   // A tile dead; region reused

    // ===== Phase 3: epilogue -> xp B-frag (bf16), u (f32), scores (f32) =====
    {
        const float* bu = (const float*)(ws + BU_OFF);
        const float* bs = (const float*)(ws + BS_OFF);
        #pragma unroll
        for (int i = 0; i < 3; ++i) {
            if (i < nf) {
                int n = nts[i] * 16 + lane_lo;
                #pragma unroll
                for (int mt = 0; mt < 2; ++mt) {
                    #pragma unroll
                    for (int r4 = 0; r4 < 4; ++r4) {
                        int row = mt * 16 + lane_hi * 4 + r4;
                        float v = acc[i][mt][r4];
                        if (i == 0) {                 // x_proj -> B-frag layout (k=rows)
                            float val = v + b_in[n];
                            int addr = M_XPF +
                                (((n >> 4) * 64 + ((n & 15) | ((row >> 3) << 4))) * 8
                                 + (row & 7)) * 2;
                            *(unsigned short*)(smem + addr) = f2bf(val);
                        } else if (i == 1) {          // u (f32)
                            int d = n - 128;
                            *(float*)(smem + M_U + (row * 128 + d) * 4) = v + bu[d];
                        } else {                      // scores
                            int s = n - 256;
                            *(float*)(smem + M_SC + (row * 32 + s) * 4) = v + bs[s];
                        }
                    }
                }
            }
        }
    }
    __syncthreads();

    // ===== Phase 4: softmax (4 rows/wave), write PR (k=s) + PRT (k=r) A-frags =====
    #pragma unroll
    for (int i = 0; i < 4; ++i) {
        int r = w * 4 + i;
        int s = l & 31;
        float sc = *(const float*)(smem + M_SC + (r * 32 + s) * 4);
        float mx = sc;
        #pragma unroll
        for (int m = 1; m < 32; m <<= 1) mx = fmaxf(mx, __shfl_xor(mx, m));
        float e = __expf(sc - mx);
        float sum = e;
        #pragma unroll
        for (int m = 1; m < 32; m <<= 1) sum += __shfl_xor(sum, m);
        float p = e * __builtin_amdgcn_rcpf(sum);
        if (l < 32) {
            unsigned short pb = f2bf(p);
            // PR: A[r][s]: mt=r>>4, lane=(r&15)+16*(s>>3), j=s&7
            *(unsigned short*)(smem + M_PR +
                (((r >> 4) * 64 + ((r & 15) + 16 * (s >> 3))) * 8 + (s & 7)) * 2) = pb;
            // PRT: A[s][r]: mt=s>>4, lane=(s&15)+16*(r>>3), j=r&7
            *(unsigned short*)(smem + M_PRT +
                (((s >> 4) * 64 + ((s & 15) + 16 * (r >> 3))) * 8 + (r & 7)) * 2) = pb;
        }
    }
    __syncthreads();

    float* accw = (float*)(ws + ACC_OFF + (size_t)(blockIdx.x & copy_mask) * 32768);
    float* accg = accw + 4096;

    // ===== Phase 5: read-GEMM + write-GEMM, wave w owns nt=w =====
    {
        bfrag_t pa0 = *(const bfrag_t*)(smem + M_PR + l * 16);
        bfrag_t pa1 = *(const bfrag_t*)(smem + M_PR + 1024 + l * 16);
        bfrag_t pat0 = *(const bfrag_t*)(smem + M_PRT + l * 16);
        bfrag_t pat1 = *(const bfrag_t*)(smem + M_PRT + 1024 + l * 16);
        bfrag_t bm = ((const bfrag_t*)(ws + MEMFRAG_OFF))[w * 64 + l];
        bfrag_t bx = *(const bfrag_t*)(smem + M_XPF + (w * 64 + l) * 16);

        floatx4 r0 = (floatx4){0.f, 0.f, 0.f, 0.f};
        floatx4 r1 = (floatx4){0.f, 0.f, 0.f, 0.f};
        r0 = __builtin_amdgcn_mfma_f32_16x16x32_bf16(pa0, bm, r0, 0, 0, 0);
        r1 = __builtin_amdgcn_mfma_f32_16x16x32_bf16(pa1, bm, r1, 0, 0, 0);
        floatx4 w0 = (floatx4){0.f, 0.f, 0.f, 0.f};
        floatx4 w1 = (floatx4){0.f, 0.f, 0.f, 0.f};
        w0 = __builtin_amdgcn_mfma_f32_16x16x32_bf16(pat0, bx, w0, 0, 0, 0);
        w1 = __builtin_amdgcn_mfma_f32_16x16x32_bf16(pat1, bx, w1, 0, 0, 0);

        int nc = w * 16 + lane_lo;
        #pragma unroll
        for (int r4 = 0; r4 < 4; ++r4) {
            int row = lane_hi * 4 + r4;
            *(float*)(smem + M_RC + (row * 128 + nc) * 4) = r0[r4];
            *(float*)(smem + M_RC + ((row + 16) * 128 + nc) * 4) = r1[r4];
            __hip_atomic_fetch_add(&accw[row * 128 + nc], w0[r4],
                                   __ATOMIC_RELAXED, __HIP_MEMORY_SCOPE_AGENT);
            __hip_atomic_fetch_add(&accw[(row + 16) * 128 + nc], w1[r4],
                                   __ATOMIC_RELAXED, __HIP_MEMORY_SCOPE_AGENT);
        }
    }
    __syncthreads();

    // ===== Phase 6: rc writeback (2 float4/thread) + gate sigmoids =====
    {
        const float4* rc4 = (const float4*)(smem + M_RC);
        float4* out4 = (float4*)out;
        #pragma unroll
        for (int q = 0; q < 2; ++q) {
            int idx = q * 512 + tid;                 // 1024 float4s = 32 rows x 32
            int row = idx >> 5, c4 = idx & 31;
            out4[(size_t)(row_base + row) * 32 + c4] = rc4[idx];
        }
    }
    {
        int sbase = w * 4;
        const float* gb = (const float*)(ws + GB_OFF);
        float gbr0[4], gbr1[4], ag0[4], ag1[4];
        #pragma unroll
        for (int si = 0; si < 4; ++si) {
            gbr0[si] = gb[(sbase + si) * 128 + l];
            gbr1[si] = gb[(sbase + si) * 128 + l + 64];
            ag0[si] = 0.f; ag1[si] = 0.f;
        }
        for (int r = 0; r < 32; ++r) {
            float uv0 = *(const float*)(smem + M_U + (r * 128 + l) * 4);
            float uv1 = *(const float*)(smem + M_U + (r * 128 + l + 64) * 4);
            #pragma unroll
            for (int si = 0; si < 4; ++si) {
                ag0[si] += sigm(gbr0[si] + uv0);
                ag1[si] += sigm(gbr1[si] + uv1);
            }
        }
        #pragma unroll
        for (int si = 0; si < 4; ++si) {
            __hip_atomic_fetch_add(&accg[(sbase + si) * 128 + l],      ag0[si],
                                   __ATOMIC_RELAXED, __HIP_MEMORY_SCOPE_AGENT);
            __hip_atomic_fetch_add(&accg[(sbase + si) * 128 + l + 64], ag1[si],
                                   __ATOMIC_RELAXED, __HIP_MEMORY_SCOPE_AGENT);
        }
    }
}

// ---------------- finalize: reduce copies -> new_memory ----------------
__global__ __launch_bounds__(512) void fin_kernel(
    const float* __restrict__ memv, const unsigned char* __restrict__ ws,
    float* __restrict__ out2, int ncopy)
{
    int i = blockIdx.x * 512 + threadIdx.x;   // 8 x 512 = 4096
    const float* base = (const float*)(ws + ACC_OFF);
    float aw = 0.f, ag = 0.f;
    #pragma unroll 8
    for (int c = 0; c < ncopy; ++c) {
        aw += base[c * 8192 + i];
        ag += base[c * 8192 + 4096 + i];
    }
    ag *= (1.f / 16384.f);
    aw *= (1.f / 16384.f);
    out2[i] = memv[i] * (1.f - ag) + aw * ag;
}

// ---------------- launcher ----------------
extern "C" void kernel_launch(void* const* d_in, const int* in_sizes, int n_in,
                              void* d_out, int out_size, void* d_ws, size_t ws_size,
                              hipStream_t stream)
{
    (void)in_sizes; (void)n_in; (void)out_size;
    const float* x      = (const float*)d_in[0];
    const float* memv   = (const float*)d_in[1];
    const float* ln_g   = (const float*)d_in[2];
    const float* ln_b   = (const float*)d_in[3];
    const float* w_in   = (const float*)d_in[4];
    const float* b_in   = (const float*)d_in[5];
    const float* w_gate = (const float*)d_in[6];
    const float* b_gate = (const float*)d_in[7];
    float* out = (float*)d_out;
    unsigned char* ws = (unsigned char*)d_ws;

    int ncopy = (ws_size >= (size_t)ACC_OFF + 64 * 32768) ? 64 : 32;

    hipLaunchKernelGGL(prep_kernel, dim3(289), dim3(256), 0, stream,
                       memv, w_in, b_in, w_gate, b_gate, ws, ncopy);
    hipLaunchKernelGGL(main_kernel, dim3(512), dim3(512), 0, stream,
                       x, ln_g, ln_b, b_in, ws, out, ncopy - 1);
    hipLaunchKernelGGL(fin_kernel, dim3(8), dim3(512), 0, stream,
                       memv, ws, out + 2097152, ncopy);
}